// Round 10
// baseline (220.935 us; speedup 1.0000x reference)
//
#include <hip/hip_runtime.h>
#include <math.h>

// ============================================================================
// INSTRUMENTATION ROUND (R10): identical kernels to the verified 167.2 µs R9
// version, but prep/d2/d3/d4 are each launched TWICE (all are idempotent —
// pure functions of prior-stage buffers). dur_new - 167.2 = sum of the four
// kernel times + 4 launch gaps, splitting "kernel cost" from "fixed harness
// overhead" which the fill-dominated top-5 counters cannot show.
// ============================================================================

#define N 4096
#define NB 128         // bands per column
#define BANDSZ 32      // rows per band
#define MAXDEG 128
#define NEG_SLOPE 0.2f
#define LN_EPS 1e-5f

__device__ __forceinline__ float wave_reduce_sum(float v) {
    #pragma unroll
    for (int m = 32; m >= 1; m >>= 1) v += __shfl_xor(v, m, 64);
    return v;
}
__device__ __forceinline__ float wave_reduce_max(float v) {
    #pragma unroll
    for (int m = 32; m >= 1; m >>= 1) v = fmaxf(v, __shfl_xor(v, m, 64));
    return v;
}

// row-vector (lane=col) times 64x64 row-major W via shfl broadcast.
__device__ __forceinline__ float transform_row(float hv, const float* __restrict__ W,
                                               int lane) {
    float tr = 0.f;
    #pragma unroll
    for (int k = 0; k < 64; ++k)
        tr += __shfl(hv, k, 64) * W[k * 64 + lane];
    return tr;
}

// Half-gather for the 2-wave-per-row split (dispatches 2/3/4). Softmax probs
// computed redundantly+identically in both waves; partial acc via LDS.
__device__ __forceinline__ float agg_half(int j0, int j1, int deg, float sd,
        const float* __restrict__ ssin, const float* __restrict__ hwin,
        int lane, int lo, int hi, float* Zout) {
    float e0 = -1e30f, e1 = -1e30f;
    if (lane < deg)      { float v = ssin[j0] + sd; e0 = v > 0.f ? v : NEG_SLOPE * v; }
    if (lane + 64 < deg) { float v = ssin[j1] + sd; e1 = v > 0.f ? v : NEG_SLOPE * v; }
    float m = wave_reduce_max(fmaxf(e0, e1));
    float p0 = (lane < deg)      ? expf(e0 - m) : 0.f;
    float p1 = (lane + 64 < deg) ? expf(e1 - m) : 0.f;
    *Zout = wave_reduce_sum(p0 + p1);
    float acc = 0.f;
    int hi0 = min(hi, 64);
    #pragma unroll 8
    for (int n = lo; n < hi0; ++n) {          // slots below 64
        int   jj = __shfl(j0, n, 64);
        float p  = __shfl(p0, n, 64);
        acc += p * hwin[jj * 64 + lane];
    }
    #pragma unroll 2
    for (int n = (lo > 64 ? lo : 64); n < hi; ++n) {   // slots >= 64
        int   jj = __shfl(j1, n - 64, 64);
        float p  = __shfl(p1, n - 64, 64);
        acc += p * hwin[jj * 64 + lane];
    }
    return acc;
}

// ---- dispatch 1: BITMASK neighbor build (bm[band][col], uint4 coalesced
// store) + emb MLP + layer-0 transform. Verified R5/R8 structure.
__global__ void __launch_bounds__(256) prep_kernel(
        const float4* __restrict__ adj4, const int* __restrict__ timestep,
        const float* __restrict__ arr, const float* __restrict__ dep,
        const float* __restrict__ hard,
        const float* __restrict__ w1, const float* __restrict__ b1,
        const float* __restrict__ w2, const float* __restrict__ b2,
        const float* __restrict__ W0, const float* __restrict__ asrc,
        const float* __restrict__ adst,
        uint4* __restrict__ bm4,
        float* __restrict__ x, float* __restrict__ hwA,
        float* __restrict__ ssA, float* __restrict__ sdA) {
    int wave = threadIdx.x >> 6;
    int lane = threadIdx.x & 63;
    if (blockIdx.x < 512) {
        int t    = blockIdx.x * 256 + threadIdx.x;   // 0..131071
        int cg   = t & 1023;                          // col group (4 cols)
        int band = t >> 10;                           // 0..127
        int jbase = band * BANDSZ;
        unsigned m0 = 0u, m1 = 0u, m2 = 0u, m3 = 0u;
        #pragma unroll
        for (int batch = 0; batch < 4; ++batch) {
            float4 a[8];
            #pragma unroll
            for (int u = 0; u < 8; ++u)
                a[u] = adj4[(size_t)(jbase + batch * 8 + u) * 1024 + cg];
            #pragma unroll
            for (int u = 0; u < 8; ++u) {
                unsigned bit = batch * 8 + u;
                m0 |= (unsigned)(a[u].x != 0.f) << bit;
                m1 |= (unsigned)(a[u].y != 0.f) << bit;
                m2 |= (unsigned)(a[u].z != 0.f) << bit;
                m3 |= (unsigned)(a[u].w != 0.f) << bit;
            }
        }
        uint4 m; m.x = m0; m.y = m1; m.z = m2; m.w = m3;
        bm4[band * 1024 + cg] = m;                    // bm[band][i0..i0+3]
    } else {
        int row = (blockIdx.x - 512) * 4 + wave;      // one row per wave
        float ts = (float)(*timestep);
        float pr = (ts - arr[row]) / (dep[row] - arr[row]);
        float hd = hard[row];
        float t  = pr * w1[lane] + hd * w1[64 + lane] + b1[lane];
        float xv = b2[lane];
        #pragma unroll
        for (int k = 0; k < 64; ++k)
            xv += __shfl(t, k, 64) * w2[k * 64 + lane];
        x[row * 64 + lane] = xv;
        float tr = transform_row(xv, W0, lane);
        hwA[row * 64 + lane] = tr;
        float s1 = wave_reduce_sum(tr * asrc[lane]);
        float s2 = wave_reduce_sum(tr * adst[lane]);
        if (lane == 0) { ssA[row] = s1; sdA[row] = s2; }
    }
}

// ---- dispatch 2: mask->index compaction + layer-0 aggregate + relu +
// layer-1 transform + scores. Wave-pair split (verified R9).
__global__ void __launch_bounds__(512, 8) compact_agg_tr(
        const unsigned* __restrict__ bm,
        const float* __restrict__ hwin, const float* __restrict__ ssin,
        const float* __restrict__ sdin, const float* __restrict__ b,
        const float* __restrict__ W, const float* __restrict__ asrc,
        const float* __restrict__ adst,
        int* __restrict__ nbr_c, int* __restrict__ deg_arr,
        float* __restrict__ hwout, float* __restrict__ ssout,
        float* __restrict__ sdout) {
    __shared__ int lds[4][MAXDEG];
    __shared__ float accb[4][64];
    int w    = threadIdx.x >> 6;      // 0..7
    int lane = threadIdx.x & 63;
    int r    = w >> 1;                // row slot 0..3
    int half = w & 1;
    int i = blockIdx.x * 4 + r;
    unsigned m0 = bm[(2 * lane)     * N + i];
    unsigned m1 = bm[(2 * lane + 1) * N + i];
    int selfband = i >> 5;                    // self-loop: bit i&31 of band i>>5
    if (2 * lane     == selfband) m0 |= 1u << (i & 31);
    if (2 * lane + 1 == selfband) m1 |= 1u << (i & 31);
    int c0 = __popc(m0);
    int c1 = __popc(m1);
    int c  = c0 + c1;
    int inc = c;
    #pragma unroll
    for (int s = 1; s < 64; s <<= 1) {
        int t = __shfl_up(inc, s, 64);
        if (lane >= s) inc += t;
    }
    int off = inc - c;
    int deg = min(__shfl(inc, 63, 64), MAXDEG);
    {   // both waves write identical values — benign duplicate stores
        int o = off;
        unsigned mm = m0; int base = (2 * lane) * 32;
        while (mm) { int bit = __ffs(mm) - 1; mm &= mm - 1;
                     if (o < MAXDEG) lds[r][o] = base + bit; ++o; }
        mm = m1; base = (2 * lane + 1) * 32;
        while (mm) { int bit = __ffs(mm) - 1; mm &= mm - 1;
                     if (o < MAXDEG) lds[r][o] = base + bit; ++o; }
    }
    __syncthreads();
    int j0 = (lane < deg)      ? lds[r][lane]      : 0;
    int j1 = (lane + 64 < deg) ? lds[r][lane + 64] : 0;
    if (!half) {
        if (lane < deg)      nbr_c[i * MAXDEG + lane]      = j0;
        if (lane + 64 < deg) nbr_c[i * MAXDEG + lane + 64] = j1;
        if (lane == 0) deg_arr[i] = deg;
    }
    int h = (deg + 1) >> 1;
    float Z;
    float acc = agg_half(j0, j1, deg, sdin[i], ssin, hwin, lane,
                         half ? h : 0, half ? deg : h, &Z);
    if (half) accb[r][lane] = acc;
    __syncthreads();
    if (!half) {
        acc += accb[r][lane];
        float hv = fmaxf(acc / Z + b[lane], 0.f);
        float tr = transform_row(hv, W, lane);
        hwout[i * 64 + lane] = tr;
        float s1 = wave_reduce_sum(tr * asrc[lane]);
        float s2 = wave_reduce_sum(tr * adst[lane]);
        if (lane == 0) { ssout[i] = s1; sdout[i] = s2; }
    }
}

// ---- dispatch 3: layer-1 aggregate + relu + layer-2 transform + scores.
__global__ void __launch_bounds__(512, 8) agg_tr(
        const float* __restrict__ hwin, const float* __restrict__ ssin,
        const float* __restrict__ sdin, const int* __restrict__ nbr_c,
        const int* __restrict__ deg_arr, const float* __restrict__ b,
        const float* __restrict__ W, const float* __restrict__ asrc,
        const float* __restrict__ adst,
        float* __restrict__ hwout, float* __restrict__ ssout,
        float* __restrict__ sdout) {
    __shared__ float accb[4][64];
    int w    = threadIdx.x >> 6;      // 0..7
    int lane = threadIdx.x & 63;
    int r    = w >> 1;                // row slot 0..3
    int half = w & 1;
    int i = blockIdx.x * 4 + r;
    int deg = deg_arr[i];
    int j0 = (lane < deg)      ? nbr_c[i * MAXDEG + lane]      : 0;
    int j1 = (lane + 64 < deg) ? nbr_c[i * MAXDEG + lane + 64] : 0;
    int h  = (deg + 1) >> 1;
    float Z;
    float acc = agg_half(j0, j1, deg, sdin[i], ssin, hwin, lane,
                         half ? h : 0, half ? deg : h, &Z);
    if (half) accb[r][lane] = acc;
    __syncthreads();
    if (!half) {
        acc += accb[r][lane];
        float hv = fmaxf(acc / Z + b[lane], 0.f);
        float tr = transform_row(hv, W, lane);
        hwout[i * 64 + lane] = tr;
        float s1 = wave_reduce_sum(tr * asrc[lane]);
        float s2 = wave_reduce_sum(tr * adst[lane]);
        if (lane == 0) { ssout[i] = s1; sdout[i] = s2; }
    }
}

// ---- dispatch 4: layer-2 aggregate + residual + layernorm + val_w dot.
// Atomic-free finish (verified R8: -14.6 µs).
__global__ void __launch_bounds__(512, 8) agg_final(
        const float* __restrict__ hwin, const float* __restrict__ ssin,
        const float* __restrict__ sdin, const int* __restrict__ nbr_c,
        const int* __restrict__ deg_arr, const float* __restrict__ b,
        const float* __restrict__ x, const float* __restrict__ vw,
        float* __restrict__ partials) {
    __shared__ float accb[4][64];
    __shared__ float sp[4];
    int w    = threadIdx.x >> 6;
    int lane = threadIdx.x & 63;
    int r    = w >> 1;
    int half = w & 1;
    int i = blockIdx.x * 4 + r;
    int deg = deg_arr[i];
    int j0 = (lane < deg)      ? nbr_c[i * MAXDEG + lane]      : 0;
    int j1 = (lane + 64 < deg) ? nbr_c[i * MAXDEG + lane + 64] : 0;
    int h  = (deg + 1) >> 1;
    float Z;
    float acc = agg_half(j0, j1, deg, sdin[i], ssin, hwin, lane,
                         half ? h : 0, half ? deg : h, &Z);
    if (half) accb[r][lane] = acc;
    __syncthreads();
    if (!half) {
        acc += accb[r][lane];
        float hv = acc / Z + b[lane];
        float v  = x[i * 64 + lane] + hv;
        float mu = wave_reduce_sum(v) * (1.f / 64.f);
        float d  = v - mu;
        float var = wave_reduce_sum(d * d) * (1.f / 64.f);
        float ln  = d * rsqrtf(var + LN_EPS);
        float part = wave_reduce_sum(ln * vw[lane]);
        if (lane == 0) sp[r] = part;
    }
    __syncthreads();
    if (threadIdx.x == 0)
        partials[blockIdx.x] = sp[0] + sp[1] + sp[2] + sp[3];
}

// ---- dispatch 5: reduce 1024 block partials (fixed order) + relu.
__global__ void __launch_bounds__(256) finish_kernel(
        const float* __restrict__ partials, const float* __restrict__ vb,
        float* __restrict__ out) {
    __shared__ float sw[4];
    int lane = threadIdx.x & 63;
    int wave = threadIdx.x >> 6;
    float s = partials[threadIdx.x] + partials[threadIdx.x + 256]
            + partials[threadIdx.x + 512] + partials[threadIdx.x + 768];
    s = wave_reduce_sum(s);
    if (lane == 0) sw[wave] = s;
    __syncthreads();
    if (threadIdx.x == 0) {
        float t = sw[0] + sw[1] + sw[2] + sw[3];
        out[0] = fmaxf(t * (1.f / (float)N) + vb[0], 0.f);
    }
}

extern "C" void kernel_launch(void* const* d_in, const int* in_sizes, int n_in,
                              void* d_out, int out_size, void* d_ws, size_t ws_size,
                              hipStream_t stream) {
    const float4* adj4      = (const float4*)d_in[0];
    const int*   timestep   = (const int*)  d_in[1];
    const float* arrivals   = (const float*)d_in[2];
    const float* departures = (const float*)d_in[3];
    const float* hard       = (const float*)d_in[4];
    // d_in[5] active_agents: unused by reference
    const float* emb_w1     = (const float*)d_in[6];
    const float* emb_b1     = (const float*)d_in[7];
    const float* emb_w2     = (const float*)d_in[8];
    const float* emb_b2     = (const float*)d_in[9];
    const float* gat_w      = (const float*)d_in[10];
    const float* gat_asrc   = (const float*)d_in[11];
    const float* gat_adst   = (const float*)d_in[12];
    const float* gat_b      = (const float*)d_in[13];
    const float* val_w      = (const float*)d_in[14];
    const float* val_b      = (const float*)d_in[15];

    const size_t MB = 1u << 20;
    char* ws = (char*)d_ws;
    unsigned* bm   = (unsigned*)(ws);              // 2 MB (128 bands x 4096 cols)
    int*   nbr_c   = (int*)  (ws + 4 * MB);        // 2 MB
    int*   deg_arr = (int*)  (ws + 6 * MB);        // 16 KB
    float* x       = (float*)(ws + 7 * MB);        // 1 MB
    float* hwA     = (float*)(ws + 8 * MB);        // 1 MB
    float* hwB     = (float*)(ws + 9 * MB);        // 1 MB
    float* ssA     = (float*)(ws + 10 * MB);
    float* sdA     = (float*)(ws + 10 * MB + 65536);
    float* ssB     = (float*)(ws + 10 * MB + 131072);
    float* sdB     = (float*)(ws + 10 * MB + 196608);
    float* partials= (float*)(ws + 11 * MB);       // 4 KB (1024 floats)

    // Each of prep/d2/d3/d4 launched TWICE (idempotent) — timing probe.
    for (int rep = 0; rep < 2; ++rep)
        prep_kernel<<<1536, 256, 0, stream>>>(adj4, timestep, arrivals, departures,
                                              hard, emb_w1, emb_b1, emb_w2, emb_b2,
                                              gat_w, gat_asrc, gat_adst,
                                              (uint4*)bm, x, hwA, ssA, sdA);
    for (int rep = 0; rep < 2; ++rep)
        compact_agg_tr<<<N / 4, 512, 0, stream>>>(bm, hwA, ssA, sdA, gat_b,
                                                  gat_w + 64 * 64, gat_asrc + 64,
                                                  gat_adst + 64,
                                                  nbr_c, deg_arr, hwB, ssB, sdB);
    for (int rep = 0; rep < 2; ++rep)
        agg_tr<<<N / 4, 512, 0, stream>>>(hwB, ssB, sdB, nbr_c, deg_arr, gat_b + 64,
                                          gat_w + 2 * 64 * 64, gat_asrc + 128,
                                          gat_adst + 128, hwA, ssA, sdA);
    for (int rep = 0; rep < 2; ++rep)
        agg_final<<<N / 4, 512, 0, stream>>>(hwA, ssA, sdA, nbr_c, deg_arr,
                                             gat_b + 128, x, val_w, partials);
    finish_kernel<<<1, 256, 0, stream>>>(partials, val_b, (float*)d_out);
    (void)in_sizes; (void)n_in; (void)out_size; (void)ws_size;
}

// Round 11
// 156.475 us; speedup vs baseline: 1.4120x; 1.4120x over previous
//
#include <hip/hip_runtime.h>
#include <math.h>

#define N 4096
#define NB 128         // bands per column
#define BANDSZ 32      // rows per band
#define MAXDEG 128
#define NEG_SLOPE 0.2f
#define LN_EPS 1e-5f

__device__ __forceinline__ float wave_reduce_sum(float v) {
    #pragma unroll
    for (int m = 32; m >= 1; m >>= 1) v += __shfl_xor(v, m, 64);
    return v;
}
__device__ __forceinline__ float wave_reduce_max(float v) {
    #pragma unroll
    for (int m = 32; m >= 1; m >>= 1) v = fmaxf(v, __shfl_xor(v, m, 64));
    return v;
}

// GEMV tr[lane] = sum_k hv[k]*W[k*64+lane] via wave-private LDS staging +
// uniform-address ds_read_b128 broadcast (4 values/LDS-op) — replaces 64
// ds_bpermute (R10: agg stages measured LDS-pipe-throughput-bound).
// Accumulation order identical to the shfl version (k ascending).
__device__ __forceinline__ float transform_row_lds(float hv,
        const float* __restrict__ W, int lane, float* stage) {
    stage[lane] = hv;          // wave-private region: no barrier needed
    float tr = 0.f;
    #pragma unroll
    for (int k4 = 0; k4 < 16; ++k4) {
        float4 h4 = *(const float4*)(stage + 4 * k4);   // uniform addr: broadcast
        tr += h4.x * W[(4 * k4 + 0) * 64 + lane];
        tr += h4.y * W[(4 * k4 + 1) * 64 + lane];
        tr += h4.z * W[(4 * k4 + 2) * 64 + lane];
        tr += h4.w * W[(4 * k4 + 3) * 64 + lane];
    }
    return tr;
}

// Half-gather for the 2-wave-per-row split. Softmax probs computed
// redundantly+identically in both waves; (j,p) staged once per wave in
// private LDS, gather reads them via uniform ds_read_b64 broadcast
// (1 LDS op/slot instead of 2 ds_bpermute). Values/order bit-identical
// to the verified R9 version (absmax 0.0).
__device__ __forceinline__ float agg_half_lds(int j0, int j1, int deg, float sd,
        const float* __restrict__ ssin, const float* __restrict__ hwin,
        int lane, int lo, int hi, float* Zout, uint2* jp) {
    float e0 = -1e30f, e1 = -1e30f;
    if (lane < deg)      { float v = ssin[j0] + sd; e0 = v > 0.f ? v : NEG_SLOPE * v; }
    if (lane + 64 < deg) { float v = ssin[j1] + sd; e1 = v > 0.f ? v : NEG_SLOPE * v; }
    float m = wave_reduce_max(fmaxf(e0, e1));
    float p0 = (lane < deg)      ? expf(e0 - m) : 0.f;
    float p1 = (lane + 64 < deg) ? expf(e1 - m) : 0.f;
    *Zout = wave_reduce_sum(p0 + p1);
    uint2 s0; s0.x = (unsigned)j0; s0.y = __float_as_uint(p0);
    uint2 s1; s1.x = (unsigned)j1; s1.y = __float_as_uint(p1);
    jp[lane]      = s0;        // wave-private staging
    jp[lane + 64] = s1;
    float acc = 0.f;
    int hi0 = min(hi, 64);
    #pragma unroll 8
    for (int n = lo; n < hi0; ++n) {
        uint2 e = jp[n];                        // uniform addr broadcast
        acc += __uint_as_float(e.y) * hwin[e.x * 64 + lane];
    }
    #pragma unroll 2
    for (int n = (lo > 64 ? lo : 64); n < hi; ++n) {
        uint2 e = jp[n];
        acc += __uint_as_float(e.y) * hwin[e.x * 64 + lane];
    }
    return acc;
}

// ---- dispatch 1: BITMASK neighbor build (bm[band][col], uint4 coalesced
// store) + emb MLP + layer-0 transform (LDS-staged GEMVs).
__global__ void __launch_bounds__(256) prep_kernel(
        const float4* __restrict__ adj4, const int* __restrict__ timestep,
        const float* __restrict__ arr, const float* __restrict__ dep,
        const float* __restrict__ hard,
        const float* __restrict__ w1, const float* __restrict__ b1,
        const float* __restrict__ w2, const float* __restrict__ b2,
        const float* __restrict__ W0, const float* __restrict__ asrc,
        const float* __restrict__ adst,
        uint4* __restrict__ bm4,
        float* __restrict__ x, float* __restrict__ hwA,
        float* __restrict__ ssA, float* __restrict__ sdA) {
    __shared__ float st[4][64];
    int wave = threadIdx.x >> 6;
    int lane = threadIdx.x & 63;
    if (blockIdx.x < 512) {
        int t    = blockIdx.x * 256 + threadIdx.x;   // 0..131071
        int cg   = t & 1023;                          // col group (4 cols)
        int band = t >> 10;                           // 0..127
        int jbase = band * BANDSZ;
        unsigned m0 = 0u, m1 = 0u, m2 = 0u, m3 = 0u;
        #pragma unroll
        for (int batch = 0; batch < 4; ++batch) {
            float4 a[8];
            #pragma unroll
            for (int u = 0; u < 8; ++u)
                a[u] = adj4[(size_t)(jbase + batch * 8 + u) * 1024 + cg];
            #pragma unroll
            for (int u = 0; u < 8; ++u) {
                unsigned bit = batch * 8 + u;
                m0 |= (unsigned)(a[u].x != 0.f) << bit;
                m1 |= (unsigned)(a[u].y != 0.f) << bit;
                m2 |= (unsigned)(a[u].z != 0.f) << bit;
                m3 |= (unsigned)(a[u].w != 0.f) << bit;
            }
        }
        uint4 m; m.x = m0; m.y = m1; m.z = m2; m.w = m3;
        bm4[band * 1024 + cg] = m;                    // bm[band][i0..i0+3]
    } else {
        int row = (blockIdx.x - 512) * 4 + wave;      // one row per wave
        float ts = (float)(*timestep);
        float pr = (ts - arr[row]) / (dep[row] - arr[row]);
        float hd = hard[row];
        float t  = pr * w1[lane] + hd * w1[64 + lane] + b1[lane];
        float xv = b2[lane] + transform_row_lds(t, w2, lane, st[wave]);
        x[row * 64 + lane] = xv;
        float tr = transform_row_lds(xv, W0, lane, st[wave]);
        hwA[row * 64 + lane] = tr;
        float s1 = wave_reduce_sum(tr * asrc[lane]);
        float s2 = wave_reduce_sum(tr * adst[lane]);
        if (lane == 0) { ssA[row] = s1; sdA[row] = s2; }
    }
}

// ---- dispatch 2: mask->index compaction + layer-0 aggregate + relu +
// layer-1 transform + scores. Wave-pair split (verified R9) with LDS-staged
// broadcasts (R10).
__global__ void __launch_bounds__(512, 8) compact_agg_tr(
        const unsigned* __restrict__ bm,
        const float* __restrict__ hwin, const float* __restrict__ ssin,
        const float* __restrict__ sdin, const float* __restrict__ b,
        const float* __restrict__ W, const float* __restrict__ asrc,
        const float* __restrict__ adst,
        int* __restrict__ nbr_c, int* __restrict__ deg_arr,
        float* __restrict__ hwout, float* __restrict__ ssout,
        float* __restrict__ sdout) {
    __shared__ int lds[4][MAXDEG];
    __shared__ float accb[4][64];
    __shared__ uint2 jp[8][128];
    int w    = threadIdx.x >> 6;      // 0..7
    int lane = threadIdx.x & 63;
    int r    = w >> 1;                // row slot 0..3
    int half = w & 1;
    int i = blockIdx.x * 4 + r;
    unsigned m0 = bm[(2 * lane)     * N + i];
    unsigned m1 = bm[(2 * lane + 1) * N + i];
    int selfband = i >> 5;                    // self-loop: bit i&31 of band i>>5
    if (2 * lane     == selfband) m0 |= 1u << (i & 31);
    if (2 * lane + 1 == selfband) m1 |= 1u << (i & 31);
    int c0 = __popc(m0);
    int c1 = __popc(m1);
    int c  = c0 + c1;
    int inc = c;
    #pragma unroll
    for (int s = 1; s < 64; s <<= 1) {
        int t = __shfl_up(inc, s, 64);
        if (lane >= s) inc += t;
    }
    int off = inc - c;
    int deg = min(__shfl(inc, 63, 64), MAXDEG);
    {   // both waves write identical values — benign duplicate stores
        int o = off;
        unsigned mm = m0; int base = (2 * lane) * 32;
        while (mm) { int bit = __ffs(mm) - 1; mm &= mm - 1;
                     if (o < MAXDEG) lds[r][o] = base + bit; ++o; }
        mm = m1; base = (2 * lane + 1) * 32;
        while (mm) { int bit = __ffs(mm) - 1; mm &= mm - 1;
                     if (o < MAXDEG) lds[r][o] = base + bit; ++o; }
    }
    __syncthreads();
    int j0 = (lane < deg)      ? lds[r][lane]      : 0;
    int j1 = (lane + 64 < deg) ? lds[r][lane + 64] : 0;
    if (!half) {
        if (lane < deg)      nbr_c[i * MAXDEG + lane]      = j0;
        if (lane + 64 < deg) nbr_c[i * MAXDEG + lane + 64] = j1;
        if (lane == 0) deg_arr[i] = deg;
    }
    int h = (deg + 1) >> 1;
    float Z;
    float acc = agg_half_lds(j0, j1, deg, sdin[i], ssin, hwin, lane,
                             half ? h : 0, half ? deg : h, &Z, jp[w]);
    if (half) accb[r][lane] = acc;
    __syncthreads();
    if (!half) {
        acc += accb[r][lane];
        float hv = fmaxf(acc / Z + b[lane], 0.f);
        float tr = transform_row_lds(hv, W, lane, accb[r]);  // reuse accb as stage
        hwout[i * 64 + lane] = tr;
        float s1 = wave_reduce_sum(tr * asrc[lane]);
        float s2 = wave_reduce_sum(tr * adst[lane]);
        if (lane == 0) { ssout[i] = s1; sdout[i] = s2; }
    }
}

// ---- dispatch 3: layer-1 aggregate + relu + layer-2 transform + scores.
__global__ void __launch_bounds__(512, 8) agg_tr(
        const float* __restrict__ hwin, const float* __restrict__ ssin,
        const float* __restrict__ sdin, const int* __restrict__ nbr_c,
        const int* __restrict__ deg_arr, const float* __restrict__ b,
        const float* __restrict__ W, const float* __restrict__ asrc,
        const float* __restrict__ adst,
        float* __restrict__ hwout, float* __restrict__ ssout,
        float* __restrict__ sdout) {
    __shared__ float accb[4][64];
    __shared__ uint2 jp[8][128];
    int w    = threadIdx.x >> 6;      // 0..7
    int lane = threadIdx.x & 63;
    int r    = w >> 1;                // row slot 0..3
    int half = w & 1;
    int i = blockIdx.x * 4 + r;
    int deg = deg_arr[i];
    int j0 = (lane < deg)      ? nbr_c[i * MAXDEG + lane]      : 0;
    int j1 = (lane + 64 < deg) ? nbr_c[i * MAXDEG + lane + 64] : 0;
    int h  = (deg + 1) >> 1;
    float Z;
    float acc = agg_half_lds(j0, j1, deg, sdin[i], ssin, hwin, lane,
                             half ? h : 0, half ? deg : h, &Z, jp[w]);
    if (half) accb[r][lane] = acc;
    __syncthreads();
    if (!half) {
        acc += accb[r][lane];
        float hv = fmaxf(acc / Z + b[lane], 0.f);
        float tr = transform_row_lds(hv, W, lane, accb[r]);
        hwout[i * 64 + lane] = tr;
        float s1 = wave_reduce_sum(tr * asrc[lane]);
        float s2 = wave_reduce_sum(tr * adst[lane]);
        if (lane == 0) { ssout[i] = s1; sdout[i] = s2; }
    }
}

// ---- dispatch 4: layer-2 aggregate + residual + layernorm + val_w dot.
// Atomic-free finish (verified R8: -14.6 µs).
__global__ void __launch_bounds__(512, 8) agg_final(
        const float* __restrict__ hwin, const float* __restrict__ ssin,
        const float* __restrict__ sdin, const int* __restrict__ nbr_c,
        const int* __restrict__ deg_arr, const float* __restrict__ b,
        const float* __restrict__ x, const float* __restrict__ vw,
        float* __restrict__ partials) {
    __shared__ float accb[4][64];
    __shared__ uint2 jp[8][128];
    __shared__ float sp[4];
    int w    = threadIdx.x >> 6;
    int lane = threadIdx.x & 63;
    int r    = w >> 1;
    int half = w & 1;
    int i = blockIdx.x * 4 + r;
    int deg = deg_arr[i];
    int j0 = (lane < deg)      ? nbr_c[i * MAXDEG + lane]      : 0;
    int j1 = (lane + 64 < deg) ? nbr_c[i * MAXDEG + lane + 64] : 0;
    int h  = (deg + 1) >> 1;
    float Z;
    float acc = agg_half_lds(j0, j1, deg, sdin[i], ssin, hwin, lane,
                             half ? h : 0, half ? deg : h, &Z, jp[w]);
    if (half) accb[r][lane] = acc;
    __syncthreads();
    if (!half) {
        acc += accb[r][lane];
        float hv = acc / Z + b[lane];
        float v  = x[i * 64 + lane] + hv;
        float mu = wave_reduce_sum(v) * (1.f / 64.f);
        float d  = v - mu;
        float var = wave_reduce_sum(d * d) * (1.f / 64.f);
        float ln  = d * rsqrtf(var + LN_EPS);
        float part = wave_reduce_sum(ln * vw[lane]);
        if (lane == 0) sp[r] = part;
    }
    __syncthreads();
    if (threadIdx.x == 0)
        partials[blockIdx.x] = sp[0] + sp[1] + sp[2] + sp[3];
}

// ---- dispatch 5: reduce 1024 block partials (fixed order) + relu.
__global__ void __launch_bounds__(256) finish_kernel(
        const float* __restrict__ partials, const float* __restrict__ vb,
        float* __restrict__ out) {
    __shared__ float sw[4];
    int lane = threadIdx.x & 63;
    int wave = threadIdx.x >> 6;
    float s = partials[threadIdx.x] + partials[threadIdx.x + 256]
            + partials[threadIdx.x + 512] + partials[threadIdx.x + 768];
    s = wave_reduce_sum(s);
    if (lane == 0) sw[wave] = s;
    __syncthreads();
    if (threadIdx.x == 0) {
        float t = sw[0] + sw[1] + sw[2] + sw[3];
        out[0] = fmaxf(t * (1.f / (float)N) + vb[0], 0.f);
    }
}

extern "C" void kernel_launch(void* const* d_in, const int* in_sizes, int n_in,
                              void* d_out, int out_size, void* d_ws, size_t ws_size,
                              hipStream_t stream) {
    const float4* adj4      = (const float4*)d_in[0];
    const int*   timestep   = (const int*)  d_in[1];
    const float* arrivals   = (const float*)d_in[2];
    const float* departures = (const float*)d_in[3];
    const float* hard       = (const float*)d_in[4];
    // d_in[5] active_agents: unused by reference
    const float* emb_w1     = (const float*)d_in[6];
    const float* emb_b1     = (const float*)d_in[7];
    const float* emb_w2     = (const float*)d_in[8];
    const float* emb_b2     = (const float*)d_in[9];
    const float* gat_w      = (const float*)d_in[10];
    const float* gat_asrc   = (const float*)d_in[11];
    const float* gat_adst   = (const float*)d_in[12];
    const float* gat_b      = (const float*)d_in[13];
    const float* val_w      = (const float*)d_in[14];
    const float* val_b      = (const float*)d_in[15];

    const size_t MB = 1u << 20;
    char* ws = (char*)d_ws;
    unsigned* bm   = (unsigned*)(ws);              // 2 MB (128 bands x 4096 cols)
    int*   nbr_c   = (int*)  (ws + 4 * MB);        // 2 MB
    int*   deg_arr = (int*)  (ws + 6 * MB);        // 16 KB
    float* x       = (float*)(ws + 7 * MB);        // 1 MB
    float* hwA     = (float*)(ws + 8 * MB);        // 1 MB
    float* hwB     = (float*)(ws + 9 * MB);        // 1 MB
    float* ssA     = (float*)(ws + 10 * MB);
    float* sdA     = (float*)(ws + 10 * MB + 65536);
    float* ssB     = (float*)(ws + 10 * MB + 131072);
    float* sdB     = (float*)(ws + 10 * MB + 196608);
    float* partials= (float*)(ws + 11 * MB);       // 4 KB (1024 floats)

    prep_kernel<<<1536, 256, 0, stream>>>(adj4, timestep, arrivals, departures, hard,
                                          emb_w1, emb_b1, emb_w2, emb_b2,
                                          gat_w, gat_asrc, gat_adst,
                                          (uint4*)bm, x, hwA, ssA, sdA);
    compact_agg_tr<<<N / 4, 512, 0, stream>>>(bm, hwA, ssA, sdA, gat_b,
                                              gat_w + 64 * 64, gat_asrc + 64,
                                              gat_adst + 64,
                                              nbr_c, deg_arr, hwB, ssB, sdB);
    agg_tr<<<N / 4, 512, 0, stream>>>(hwB, ssB, sdB, nbr_c, deg_arr, gat_b + 64,
                                      gat_w + 2 * 64 * 64, gat_asrc + 128,
                                      gat_adst + 128, hwA, ssA, sdA);
    agg_final<<<N / 4, 512, 0, stream>>>(hwA, ssA, sdA, nbr_c, deg_arr,
                                         gat_b + 128, x, val_w, partials);
    finish_kernel<<<1, 256, 0, stream>>>(partials, val_b, (float*)d_out);
    (void)in_sizes; (void)n_in; (void)out_size; (void)ws_size;
}

// Round 13
// 151.638 us; speedup vs baseline: 1.4570x; 1.0319x over previous
//
#include <hip/hip_runtime.h>
#include <math.h>

#define N 4096
#define NB 128         // bands per column
#define BANDSZ 32      // rows per band
#define MAXDEG 128
#define NEG_SLOPE 0.2f
#define LN_EPS 1e-5f

__device__ __forceinline__ float wave_reduce_sum(float v) {
    #pragma unroll
    for (int m = 32; m >= 1; m >>= 1) v += __shfl_xor(v, m, 64);
    return v;
}
__device__ __forceinline__ float wave_reduce_max(float v) {
    #pragma unroll
    for (int m = 32; m >= 1; m >>= 1) v = fmaxf(v, __shfl_xor(v, m, 64));
    return v;
}

// GEMV tr[lane] = sum_k hv[k]*W[k*64+lane] via wave-private LDS staging +
// uniform-address ds_read_b128 broadcast (verified R11: -10.7 µs).
__device__ __forceinline__ float transform_row_lds(float hv,
        const float* __restrict__ W, int lane, float* stage) {
    stage[lane] = hv;          // wave-private region: no barrier needed
    float tr = 0.f;
    #pragma unroll
    for (int k4 = 0; k4 < 16; ++k4) {
        float4 h4 = *(const float4*)(stage + 4 * k4);   // uniform addr: broadcast
        tr += h4.x * W[(4 * k4 + 0) * 64 + lane];
        tr += h4.y * W[(4 * k4 + 1) * 64 + lane];
        tr += h4.z * W[(4 * k4 + 2) * 64 + lane];
        tr += h4.w * W[(4 * k4 + 3) * 64 + lane];
    }
    return tr;
}

// 4-wide gather over staged per-row (j, p) arrays: uniform int4/float4 LDS
// broadcasts (2 LDS ops / 4 slots). FMA order is n-ascending — bit-identical
// to the verified scalar gather.
__device__ __forceinline__ float gather4(const int* jarr, const float* parr,
        const float* __restrict__ hwin, int lane, int lo, int hi) {
    float acc = 0.f;
    int n = lo;
    for (; n < hi && (n & 3); ++n)
        acc += parr[n] * hwin[jarr[n] * 64 + lane];
    for (; n + 4 <= hi; n += 4) {
        int4   j4 = *(const int4*)  (jarr + n);
        float4 p4 = *(const float4*)(parr + n);
        acc += p4.x * hwin[j4.x * 64 + lane];
        acc += p4.y * hwin[j4.y * 64 + lane];
        acc += p4.z * hwin[j4.z * 64 + lane];
        acc += p4.w * hwin[j4.w * 64 + lane];
    }
    for (; n < hi; ++n)
        acc += parr[n] * hwin[jarr[n] * 64 + lane];
    return acc;
}

// ---- dispatch 1: BITMASK neighbor build (bm[band][col], uint4 coalesced
// store) + emb MLP + layer-0 transform (LDS-staged GEMVs). Verified R11.
__global__ void __launch_bounds__(256) prep_kernel(
        const float4* __restrict__ adj4, const int* __restrict__ timestep,
        const float* __restrict__ arr, const float* __restrict__ dep,
        const float* __restrict__ hard,
        const float* __restrict__ w1, const float* __restrict__ b1,
        const float* __restrict__ w2, const float* __restrict__ b2,
        const float* __restrict__ W0, const float* __restrict__ asrc,
        const float* __restrict__ adst,
        uint4* __restrict__ bm4,
        float* __restrict__ x, float* __restrict__ hwA,
        float* __restrict__ ssA, float* __restrict__ sdA) {
    __shared__ float st[4][64];
    int wave = threadIdx.x >> 6;
    int lane = threadIdx.x & 63;
    if (blockIdx.x < 512) {
        int t    = blockIdx.x * 256 + threadIdx.x;   // 0..131071
        int cg   = t & 1023;                          // col group (4 cols)
        int band = t >> 10;                           // 0..127
        int jbase = band * BANDSZ;
        unsigned m0 = 0u, m1 = 0u, m2 = 0u, m3 = 0u;
        #pragma unroll
        for (int batch = 0; batch < 4; ++batch) {
            float4 a[8];
            #pragma unroll
            for (int u = 0; u < 8; ++u)
                a[u] = adj4[(size_t)(jbase + batch * 8 + u) * 1024 + cg];
            #pragma unroll
            for (int u = 0; u < 8; ++u) {
                unsigned bit = batch * 8 + u;
                m0 |= (unsigned)(a[u].x != 0.f) << bit;
                m1 |= (unsigned)(a[u].y != 0.f) << bit;
                m2 |= (unsigned)(a[u].z != 0.f) << bit;
                m3 |= (unsigned)(a[u].w != 0.f) << bit;
            }
        }
        uint4 m; m.x = m0; m.y = m1; m.z = m2; m.w = m3;
        bm4[band * 1024 + cg] = m;                    // bm[band][i0..i0+3]
    } else {
        int row = (blockIdx.x - 512) * 4 + wave;      // one row per wave
        float ts = (float)(*timestep);
        float pr = (ts - arr[row]) / (dep[row] - arr[row]);
        float hd = hard[row];
        float t  = pr * w1[lane] + hd * w1[64 + lane] + b1[lane];
        float xv = b2[lane] + transform_row_lds(t, w2, lane, st[wave]);
        x[row * 64 + lane] = xv;
        float tr = transform_row_lds(xv, W0, lane, st[wave]);
        hwA[row * 64 + lane] = tr;
        float s1 = wave_reduce_sum(tr * asrc[lane]);
        float s2 = wave_reduce_sum(tr * adst[lane]);
        if (lane == 0) { ssA[row] = s1; sdA[row] = s2; }
    }
}

// ---- dispatch 2: mask->index compaction + layer-0 aggregate + relu +
// layer-1 transform + scores. DEDUPED wave-pair: half-0 does mask/scan/
// extract/softmax ONCE and stages (j,p,deg) in per-row LDS; barrier; both
// halves gather [0,h)/[h,deg) (verified split, bit-identical order).
__global__ void __launch_bounds__(512, 8) compact_agg_tr(
        const unsigned* __restrict__ bm,
        const float* __restrict__ hwin, const float* __restrict__ ssin,
        const float* __restrict__ sdin, const float* __restrict__ b,
        const float* __restrict__ W, const float* __restrict__ asrc,
        const float* __restrict__ adst,
        int* __restrict__ nbr_c, int* __restrict__ deg_arr,
        float* __restrict__ hwout, float* __restrict__ ssout,
        float* __restrict__ sdout) {
    __shared__ int   jarr[4][MAXDEG];
    __shared__ float parr[4][MAXDEG];
    __shared__ float accb[4][64];
    __shared__ int   degs[4];
    int w    = threadIdx.x >> 6;      // 0..7
    int lane = threadIdx.x & 63;
    int r    = w >> 1;                // row slot 0..3
    int half = w & 1;
    int i = blockIdx.x * 4 + r;
    float Z = 0.f;
    if (!half) {
        unsigned m0 = bm[(2 * lane)     * N + i];
        unsigned m1 = bm[(2 * lane + 1) * N + i];
        int selfband = i >> 5;                // self-loop: bit i&31 of band i>>5
        if (2 * lane     == selfband) m0 |= 1u << (i & 31);
        if (2 * lane + 1 == selfband) m1 |= 1u << (i & 31);
        int c0 = __popc(m0);
        int c1 = __popc(m1);
        int c  = c0 + c1;
        int inc = c;
        #pragma unroll
        for (int s = 1; s < 64; s <<= 1) {
            int t = __shfl_up(inc, s, 64);
            if (lane >= s) inc += t;
        }
        int off = inc - c;
        int deg = min(__shfl(inc, 63, 64), MAXDEG);
        {
            int o = off;
            unsigned mm = m0; int base = (2 * lane) * 32;
            while (mm) { int bit = __ffs(mm) - 1; mm &= mm - 1;
                         if (o < MAXDEG) jarr[r][o] = base + bit; ++o; }
            mm = m1; base = (2 * lane + 1) * 32;
            while (mm) { int bit = __ffs(mm) - 1; mm &= mm - 1;
                         if (o < MAXDEG) jarr[r][o] = base + bit; ++o; }
        }
        // same-wave RAW on jarr[r]: compiler orders via lgkmcnt
        int j0 = (lane < deg)      ? jarr[r][lane]      : 0;
        int j1 = (lane + 64 < deg) ? jarr[r][lane + 64] : 0;
        if (lane < deg)      nbr_c[i * MAXDEG + lane]      = j0;
        if (lane + 64 < deg) nbr_c[i * MAXDEG + lane + 64] = j1;
        if (lane == 0) { deg_arr[i] = deg; degs[r] = deg; }
        float sd = sdin[i];
        float e0 = -1e30f, e1 = -1e30f;
        if (lane < deg)      { float v = ssin[j0] + sd; e0 = v > 0.f ? v : NEG_SLOPE * v; }
        if (lane + 64 < deg) { float v = ssin[j1] + sd; e1 = v > 0.f ? v : NEG_SLOPE * v; }
        float m = wave_reduce_max(fmaxf(e0, e1));
        float p0 = (lane < deg)      ? expf(e0 - m) : 0.f;
        float p1 = (lane + 64 < deg) ? expf(e1 - m) : 0.f;
        Z = wave_reduce_sum(p0 + p1);
        parr[r][lane]      = p0;
        parr[r][lane + 64] = p1;
    }
    __syncthreads();
    int deg = degs[r];
    int h   = (deg + 1) >> 1;
    float acc = gather4(jarr[r], parr[r], hwin, lane,
                        half ? h : 0, half ? deg : h);
    if (half) accb[r][lane] = acc;
    __syncthreads();
    if (!half) {
        acc += accb[r][lane];
        float hv = fmaxf(acc / Z + b[lane], 0.f);
        float tr = transform_row_lds(hv, W, lane, accb[r]);  // reuse accb as stage
        hwout[i * 64 + lane] = tr;
        float s1 = wave_reduce_sum(tr * asrc[lane]);
        float s2 = wave_reduce_sum(tr * adst[lane]);
        if (lane == 0) { ssout[i] = s1; sdout[i] = s2; }
    }
}

// ---- dispatch 3: layer-1 aggregate + relu + layer-2 transform + scores.
// Deduped wave-pair + 4-wide gather.
__global__ void __launch_bounds__(512, 8) agg_tr(
        const float* __restrict__ hwin, const float* __restrict__ ssin,
        const float* __restrict__ sdin, const int* __restrict__ nbr_c,
        const int* __restrict__ deg_arr, const float* __restrict__ b,
        const float* __restrict__ W, const float* __restrict__ asrc,
        const float* __restrict__ adst,
        float* __restrict__ hwout, float* __restrict__ ssout,
        float* __restrict__ sdout) {
    __shared__ int   jarr[4][MAXDEG];
    __shared__ float parr[4][MAXDEG];
    __shared__ float accb[4][64];
    int w    = threadIdx.x >> 6;      // 0..7
    int lane = threadIdx.x & 63;
    int r    = w >> 1;                // row slot 0..3
    int half = w & 1;
    int i = blockIdx.x * 4 + r;
    int deg = deg_arr[i];
    float Z = 0.f;
    if (!half) {
        int j0 = (lane < deg)      ? nbr_c[i * MAXDEG + lane]      : 0;
        int j1 = (lane + 64 < deg) ? nbr_c[i * MAXDEG + lane + 64] : 0;
        float sd = sdin[i];
        float e0 = -1e30f, e1 = -1e30f;
        if (lane < deg)      { float v = ssin[j0] + sd; e0 = v > 0.f ? v : NEG_SLOPE * v; }
        if (lane + 64 < deg) { float v = ssin[j1] + sd; e1 = v > 0.f ? v : NEG_SLOPE * v; }
        float m = wave_reduce_max(fmaxf(e0, e1));
        float p0 = (lane < deg)      ? expf(e0 - m) : 0.f;
        float p1 = (lane + 64 < deg) ? expf(e1 - m) : 0.f;
        Z = wave_reduce_sum(p0 + p1);
        jarr[r][lane]      = j0;
        jarr[r][lane + 64] = j1;
        parr[r][lane]      = p0;
        parr[r][lane + 64] = p1;
    }
    __syncthreads();
    int h = (deg + 1) >> 1;
    float acc = gather4(jarr[r], parr[r], hwin, lane,
                        half ? h : 0, half ? deg : h);
    if (half) accb[r][lane] = acc;
    __syncthreads();
    if (!half) {
        acc += accb[r][lane];
        float hv = fmaxf(acc / Z + b[lane], 0.f);
        float tr = transform_row_lds(hv, W, lane, accb[r]);
        hwout[i * 64 + lane] = tr;
        float s1 = wave_reduce_sum(tr * asrc[lane]);
        float s2 = wave_reduce_sum(tr * adst[lane]);
        if (lane == 0) { ssout[i] = s1; sdout[i] = s2; }
    }
}

// ---- dispatch 4: layer-2 aggregate + residual + layernorm + val_w dot.
// Deduped wave-pair + 4-wide gather; atomic-free finish (verified R8).
__global__ void __launch_bounds__(512, 8) agg_final(
        const float* __restrict__ hwin, const float* __restrict__ ssin,
        const float* __restrict__ sdin, const int* __restrict__ nbr_c,
        const int* __restrict__ deg_arr, const float* __restrict__ b,
        const float* __restrict__ x, const float* __restrict__ vw,
        float* __restrict__ partials) {
    __shared__ int   jarr[4][MAXDEG];
    __shared__ float parr[4][MAXDEG];
    __shared__ float accb[4][64];
    __shared__ float sp[4];
    int w    = threadIdx.x >> 6;
    int lane = threadIdx.x & 63;
    int r    = w >> 1;
    int half = w & 1;
    int i = blockIdx.x * 4 + r;
    int deg = deg_arr[i];
    float Z = 0.f;
    if (!half) {
        int j0 = (lane < deg)      ? nbr_c[i * MAXDEG + lane]      : 0;
        int j1 = (lane + 64 < deg) ? nbr_c[i * MAXDEG + lane + 64] : 0;
        float sd = sdin[i];
        float e0 = -1e30f, e1 = -1e30f;
        if (lane < deg)      { float v = ssin[j0] + sd; e0 = v > 0.f ? v : NEG_SLOPE * v; }
        if (lane + 64 < deg) { float v = ssin[j1] + sd; e1 = v > 0.f ? v : NEG_SLOPE * v; }
        float m = wave_reduce_max(fmaxf(e0, e1));
        float p0 = (lane < deg)      ? expf(e0 - m) : 0.f;
        float p1 = (lane + 64 < deg) ? expf(e1 - m) : 0.f;
        Z = wave_reduce_sum(p0 + p1);
        jarr[r][lane]      = j0;
        jarr[r][lane + 64] = j1;
        parr[r][lane]      = p0;
        parr[r][lane + 64] = p1;
    }
    __syncthreads();
    int h = (deg + 1) >> 1;
    float acc = gather4(jarr[r], parr[r], hwin, lane,
                        half ? h : 0, half ? deg : h);
    if (half) accb[r][lane] = acc;
    __syncthreads();
    if (!half) {
        acc += accb[r][lane];
        float hv = acc / Z + b[lane];
        float v  = x[i * 64 + lane] + hv;
        float mu = wave_reduce_sum(v) * (1.f / 64.f);
        float d  = v - mu;
        float var = wave_reduce_sum(d * d) * (1.f / 64.f);
        float ln  = d * rsqrtf(var + LN_EPS);
        float part = wave_reduce_sum(ln * vw[lane]);
        if (lane == 0) sp[r] = part;
    }
    __syncthreads();
    if (threadIdx.x == 0)
        partials[blockIdx.x] = sp[0] + sp[1] + sp[2] + sp[3];
}

// ---- dispatch 5: reduce 1024 block partials (fixed order) + relu.
__global__ void __launch_bounds__(256) finish_kernel(
        const float* __restrict__ partials, const float* __restrict__ vb,
        float* __restrict__ out) {
    __shared__ float sw[4];
    int lane = threadIdx.x & 63;
    int wave = threadIdx.x >> 6;
    float s = partials[threadIdx.x] + partials[threadIdx.x + 256]
            + partials[threadIdx.x + 512] + partials[threadIdx.x + 768];
    s = wave_reduce_sum(s);
    if (lane == 0) sw[wave] = s;
    __syncthreads();
    if (threadIdx.x == 0) {
        float t = sw[0] + sw[1] + sw[2] + sw[3];
        out[0] = fmaxf(t * (1.f / (float)N) + vb[0], 0.f);
    }
}

extern "C" void kernel_launch(void* const* d_in, const int* in_sizes, int n_in,
                              void* d_out, int out_size, void* d_ws, size_t ws_size,
                              hipStream_t stream) {
    const float4* adj4      = (const float4*)d_in[0];
    const int*   timestep   = (const int*)  d_in[1];
    const float* arrivals   = (const float*)d_in[2];
    const float* departures = (const float*)d_in[3];
    const float* hard       = (const float*)d_in[4];
    // d_in[5] active_agents: unused by reference
    const float* emb_w1     = (const float*)d_in[6];
    const float* emb_b1     = (const float*)d_in[7];
    const float* emb_w2     = (const float*)d_in[8];
    const float* emb_b2     = (const float*)d_in[9];
    const float* gat_w      = (const float*)d_in[10];
    const float* gat_asrc   = (const float*)d_in[11];
    const float* gat_adst   = (const float*)d_in[12];
    const float* gat_b      = (const float*)d_in[13];
    const float* val_w      = (const float*)d_in[14];
    const float* val_b      = (const float*)d_in[15];

    const size_t MB = 1u << 20;
    char* ws = (char*)d_ws;
    unsigned* bm   = (unsigned*)(ws);              // 2 MB (128 bands x 4096 cols)
    int*   nbr_c   = (int*)  (ws + 4 * MB);        // 2 MB
    int*   deg_arr = (int*)  (ws + 6 * MB);        // 16 KB
    float* x       = (float*)(ws + 7 * MB);        // 1 MB
    float* hwA     = (float*)(ws + 8 * MB);        // 1 MB
    float* hwB     = (float*)(ws + 9 * MB);        // 1 MB
    float* ssA     = (float*)(ws + 10 * MB);
    float* sdA     = (float*)(ws + 10 * MB + 65536);
    float* ssB     = (float*)(ws + 10 * MB + 131072);
    float* sdB     = (float*)(ws + 10 * MB + 196608);
    float* partials= (float*)(ws + 11 * MB);       // 4 KB (1024 floats)

    prep_kernel<<<1536, 256, 0, stream>>>(adj4, timestep, arrivals, departures, hard,
                                          emb_w1, emb_b1, emb_w2, emb_b2,
                                          gat_w, gat_asrc, gat_adst,
                                          (uint4*)bm, x, hwA, ssA, sdA);
    compact_agg_tr<<<N / 4, 512, 0, stream>>>(bm, hwA, ssA, sdA, gat_b,
                                              gat_w + 64 * 64, gat_asrc + 64,
                                              gat_adst + 64,
                                              nbr_c, deg_arr, hwB, ssB, sdB);
    agg_tr<<<N / 4, 512, 0, stream>>>(hwB, ssB, sdB, nbr_c, deg_arr, gat_b + 64,
                                      gat_w + 2 * 64 * 64, gat_asrc + 128,
                                      gat_adst + 128, hwA, ssA, sdA);
    agg_final<<<N / 4, 512, 0, stream>>>(hwA, ssA, sdA, nbr_c, deg_arr,
                                         gat_b + 128, x, val_w, partials);
    finish_kernel<<<1, 256, 0, stream>>>(partials, val_b, (float*)d_out);
    (void)in_sizes; (void)n_in; (void)out_size; (void)ws_size;
}